// Round 2
// baseline (1211.513 us; speedup 1.0000x reference)
//
#include <hip/hip_runtime.h>
#include <hip/hip_fp16.h>
#include <math.h>

// Problem constants
#define B_     4
#define CIN    128
#define LEN    2048
#define DMODEL 256
#define DSTATE 16
#define NHEADS 256
#define DINNER 768
#define CONVDIM 800      // DINNER + 2*DSTATE
#define DINPROJ 1824     // 2*DINNER + 2*DSTATE + NHEADS
#define EPS_   1e-5f

__device__ __forceinline__ float silu_(float x){ return x / (1.0f + __expf(-x)); }
__device__ __forceinline__ float softplus_(float x){
    return x > 0.f ? x + log1pf(__expf(-x)) : log1pf(__expf(x));
}

// ---------------------------------------------------------------------------
// Kernel 1: conv projection  x(B,CIN,L) * proj_w(DMODEL,CIN,4), pad (1,2)
// -> u stored as (B, L, DMODEL) fp32 (lives in d_out; dead before out_proj)
// ---------------------------------------------------------------------------
__global__ __launch_bounds__(256) void k_convproj(const float* __restrict__ x,
                                                  const float* __restrict__ w,
                                                  float* __restrict__ u){
    __shared__ float xs[CIN][36];
    int blk = blockIdx.x;              // 0..255
    int b  = blk >> 6;
    int l0 = (blk & 63) << 5;          // *32
    const float* xb = x + (size_t)b * CIN * LEN;
    for (int idx = threadIdx.x; idx < CIN * 35; idx += 256){
        int ci = idx / 35, j = idx % 35;
        int gl = l0 - 1 + j;
        float v = 0.f;
        if (gl >= 0 && gl < LEN) v = xb[ci * LEN + gl];
        xs[ci][j] = v;
    }
    __syncthreads();
    int d = threadIdx.x;
    float acc[32];
    #pragma unroll
    for (int i = 0; i < 32; i++) acc[i] = 0.f;
    const float* wd = w + (size_t)d * CIN * 4;
    for (int ci = 0; ci < CIN; ci++){
        float4 wv = *(const float4*)(wd + ci * 4);
        float xv[35];
        #pragma unroll
        for (int j = 0; j < 35; j++) xv[j] = xs[ci][j];
        #pragma unroll
        for (int l = 0; l < 32; l++){
            acc[l] = fmaf(xv[l],     wv.x, acc[l]);
            acc[l] = fmaf(xv[l + 1], wv.y, acc[l]);
            acc[l] = fmaf(xv[l + 2], wv.z, acc[l]);
            acc[l] = fmaf(xv[l + 3], wv.w, acc[l]);
        }
    }
    float* ub = u + ((size_t)(b * LEN + l0)) * DMODEL + d;
    #pragma unroll
    for (int l = 0; l < 32; l++) ub[(size_t)l * DMODEL] = acc[l];
}

// ---------------------------------------------------------------------------
// Kernel 2: in_proj GEMM  [M=8192, N=1824] = u[M,256] . W[1824,256]^T
// fp32 accumulate, fp16 stores: z (768), xbc (800), dt (256, softplus+bias).
// ---------------------------------------------------------------------------
__global__ __launch_bounds__(256) void k_inproj(const float* __restrict__ u,
                                                const float* __restrict__ w,
                                                const float* __restrict__ dt_bias,
                                                __half* __restrict__ z,
                                                __half* __restrict__ xbc,
                                                __half* __restrict__ dt){
    __shared__ __align__(16) float As[16][68];
    __shared__ __align__(16) float Bs[16][68];
    const int K = DMODEL;
    int m0 = blockIdx.x * 64;
    int n0 = blockIdx.y * 64;
    int tid = threadIdx.x;
    int trow = tid >> 4, tcol = tid & 15;
    int lr = tid >> 2;
    int lk = (tid & 3) << 2;
    float acc[4][4];
    #pragma unroll
    for (int i = 0; i < 4; i++)
        #pragma unroll
        for (int j = 0; j < 4; j++) acc[i][j] = 0.f;

    for (int k0 = 0; k0 < K; k0 += 16){
        float4 av = *(const float4*)(u + (size_t)(m0 + lr) * K + k0 + lk);
        int nrow = n0 + lr;
        float4 bv = make_float4(0.f, 0.f, 0.f, 0.f);
        if (nrow < DINPROJ) bv = *(const float4*)(w + (size_t)nrow * K + k0 + lk);
        __syncthreads();
        As[lk][lr] = av.x; As[lk + 1][lr] = av.y; As[lk + 2][lr] = av.z; As[lk + 3][lr] = av.w;
        Bs[lk][lr] = bv.x; Bs[lk + 1][lr] = bv.y; Bs[lk + 2][lr] = bv.z; Bs[lk + 3][lr] = bv.w;
        __syncthreads();
        #pragma unroll
        for (int kk = 0; kk < 16; kk++){
            float4 a  = *(const float4*)&As[kk][trow << 2];
            float4 bb = *(const float4*)&Bs[kk][tcol << 2];
            acc[0][0] = fmaf(a.x, bb.x, acc[0][0]); acc[0][1] = fmaf(a.x, bb.y, acc[0][1]);
            acc[0][2] = fmaf(a.x, bb.z, acc[0][2]); acc[0][3] = fmaf(a.x, bb.w, acc[0][3]);
            acc[1][0] = fmaf(a.y, bb.x, acc[1][0]); acc[1][1] = fmaf(a.y, bb.y, acc[1][1]);
            acc[1][2] = fmaf(a.y, bb.z, acc[1][2]); acc[1][3] = fmaf(a.y, bb.w, acc[1][3]);
            acc[2][0] = fmaf(a.z, bb.x, acc[2][0]); acc[2][1] = fmaf(a.z, bb.y, acc[2][1]);
            acc[2][2] = fmaf(a.z, bb.z, acc[2][2]); acc[2][3] = fmaf(a.z, bb.w, acc[2][3]);
            acc[3][0] = fmaf(a.w, bb.x, acc[3][0]); acc[3][1] = fmaf(a.w, bb.y, acc[3][1]);
            acc[3][2] = fmaf(a.w, bb.z, acc[3][2]); acc[3][3] = fmaf(a.w, bb.w, acc[3][3]);
        }
    }
    #pragma unroll
    for (int i = 0; i < 4; i++){
        int row = m0 + (trow << 2) + i;
        #pragma unroll
        for (int j = 0; j < 4; j++){
            int col = n0 + (tcol << 2) + j;
            if (col >= DINPROJ) continue;
            float v = acc[i][j];
            if (col < DINNER)                z[(size_t)row * DINNER + col] = __float2half(v);
            else if (col < DINNER + CONVDIM) xbc[(size_t)row * CONVDIM + (col - DINNER)] = __float2half(v);
            else {
                int hh = col - (DINNER + CONVDIM);
                dt[(size_t)row * NHEADS + hh] = __float2half(softplus_(v + dt_bias[hh]));
            }
        }
    }
}

// ---------------------------------------------------------------------------
// Kernel 3: fused depthwise-conv(4-tap causal)+bias+SiLU + sequential scan.
// 16 lanes per head (lane=state n); 4 heads per 64-thread block.
// Rolling 3-deep register window per channel implements the causal conv.
// ---------------------------------------------------------------------------
__global__ __launch_bounds__(64) void k_scan(const __half* __restrict__ dtb,
                                             const __half* __restrict__ xbc,
                                             const float* __restrict__ cw,
                                             const float* __restrict__ cb,
                                             const float* __restrict__ A_log,
                                             const float* __restrict__ D_skip,
                                             __half* __restrict__ y){
    int blk = blockIdx.x;              // 0..255
    int b  = blk >> 6;
    int hg = blk & 63;
    int lane = threadIdx.x;
    int hl = lane >> 4;
    int n  = lane & 15;
    int h  = hg * 4 + hl;
    int c0 = h * 3;
    float A   = -__expf(A_log[h]);
    float Dsk = D_skip[h];
    // conv weights/biases for this lane's 5 channels
    float4 wx0 = *(const float4*)(cw + (size_t)(c0 + 0) * 4);
    float4 wx1 = *(const float4*)(cw + (size_t)(c0 + 1) * 4);
    float4 wx2 = *(const float4*)(cw + (size_t)(c0 + 2) * 4);
    float4 wBv = *(const float4*)(cw + (size_t)(DINNER + n) * 4);
    float4 wCv = *(const float4*)(cw + (size_t)(DINNER + DSTATE + n) * 4);
    float bx0 = cb[c0], bx1 = cb[c0 + 1], bx2 = cb[c0 + 2];
    float bBv = cb[DINNER + n], bCv = cb[DINNER + DSTATE + n];
    // rolling raw windows: [0]=t-3, [1]=t-2, [2]=t-1 (zeros = causal pad)
    float r0a = 0.f, r0b = 0.f, r0c = 0.f;   // x ch 0
    float r1a = 0.f, r1b = 0.f, r1c = 0.f;   // x ch 1
    float r2a = 0.f, r2b = 0.f, r2c = 0.f;   // x ch 2
    float rBa = 0.f, rBb = 0.f, rBc = 0.f;
    float rCa = 0.f, rCb = 0.f, rCc = 0.f;

    const __half* xrow = xbc + (size_t)b * LEN * CONVDIM;
    const __half* dtp  = dtb + (size_t)b * LEN * NHEADS + h;
    __half* yp = y + (size_t)b * LEN * DINNER + c0;
    float h0 = 0.f, h1 = 0.f, h2 = 0.f;
    // current-step raw values (prefetched)
    float cx0 = __half2float(xrow[c0]);
    float cx1 = __half2float(xrow[c0 + 1]);
    float cx2 = __half2float(xrow[c0 + 2]);
    float cB  = __half2float(xrow[DINNER + n]);
    float cC  = __half2float(xrow[DINNER + DSTATE + n]);
    float cdt = __half2float(dtp[0]);

    for (int t = 0; t < LEN; t++){
        int tn = (t + 1 < LEN) ? t + 1 : t;
        const __half* xr = xrow + (size_t)tn * CONVDIM;
        float nx0 = __half2float(xr[c0]);
        float nx1 = __half2float(xr[c0 + 1]);
        float nx2 = __half2float(xr[c0 + 2]);
        float nB  = __half2float(xr[DINNER + n]);
        float nC  = __half2float(xr[DINNER + DSTATE + n]);
        float ndt = __half2float(dtp[(size_t)tn * NHEADS]);

        // depthwise conv + bias + silu for step t
        float vx0 = silu_(bx0 + r0a * wx0.x + r0b * wx0.y + r0c * wx0.z + cx0 * wx0.w);
        float vx1 = silu_(bx1 + r1a * wx1.x + r1b * wx1.y + r1c * wx1.z + cx1 * wx1.w);
        float vx2 = silu_(bx2 + r2a * wx2.x + r2b * wx2.y + r2c * wx2.z + cx2 * wx2.w);
        float vB  = silu_(bBv + rBa * wBv.x + rBb * wBv.y + rBc * wBv.z + cB * wBv.w);
        float vC  = silu_(bCv + rCa * wCv.x + rCb * wCv.y + rCc * wCv.z + cC * wCv.w);
        // shift windows
        r0a = r0b; r0b = r0c; r0c = cx0;
        r1a = r1b; r1b = r1c; r1c = cx1;
        r2a = r2b; r2b = r2c; r2c = cx2;
        rBa = rBb; rBb = rBc; rBc = cB;
        rCa = rCb; rCb = rCc; rCc = cC;
        // scan update
        float dA  = __expf(cdt * A);
        float dtB = cdt * vB;
        h0 = fmaf(h0, dA, vx0 * dtB);
        h1 = fmaf(h1, dA, vx1 * dtB);
        h2 = fmaf(h2, dA, vx2 * dtB);
        float p0 = h0 * vC, p1 = h1 * vC, p2 = h2 * vC;
        #pragma unroll
        for (int m = 1; m < 16; m <<= 1){
            p0 += __shfl_xor(p0, m, 64);
            p1 += __shfl_xor(p1, m, 64);
            p2 += __shfl_xor(p2, m, 64);
        }
        if (n < 3){
            float pv = (n == 0) ? p0 : ((n == 1) ? p1 : p2);
            float xv = (n == 0) ? vx0 : ((n == 1) ? vx1 : vx2);
            yp[(size_t)t * DINNER + n] = __float2half(fmaf(Dsk, xv, pv));
        }
        cx0 = nx0; cx1 = nx1; cx2 = nx2; cB = nB; cC = nC; cdt = ndt;
    }
}

// ---------------------------------------------------------------------------
// Kernel 4: gated RMSNorm (in place on y, fp16 storage, fp32 math)
// ---------------------------------------------------------------------------
__global__ __launch_bounds__(256) void k_norm(__half* __restrict__ y,
                                              const __half* __restrict__ z,
                                              const float* __restrict__ nw){
    __shared__ float wsum[4];
    size_t r = blockIdx.x;
    int tid = threadIdx.x;
    const __half* zr = z + r * DINNER;
    __half* yr = y + r * DINNER;
    int e0 = tid, e1 = tid + 256, e2 = tid + 512;
    float t0 = __half2float(yr[e0]) * silu_(__half2float(zr[e0]));
    float t1 = __half2float(yr[e1]) * silu_(__half2float(zr[e1]));
    float t2 = __half2float(yr[e2]) * silu_(__half2float(zr[e2]));
    float ss = t0 * t0 + t1 * t1 + t2 * t2;
    #pragma unroll
    for (int m = 1; m < 64; m <<= 1) ss += __shfl_xor(ss, m, 64);
    if ((tid & 63) == 0) wsum[tid >> 6] = ss;
    __syncthreads();
    float tot = wsum[0] + wsum[1] + wsum[2] + wsum[3];
    float sc = rsqrtf(tot / (float)DINNER + EPS_);
    yr[e0] = __float2half(t0 * sc * nw[e0]);
    yr[e1] = __float2half(t1 * sc * nw[e1]);
    yr[e2] = __float2half(t2 * sc * nw[e2]);
}

// ---------------------------------------------------------------------------
// Kernel 5: out_proj GEMM  out[b,d,l] = sum_e y[b,l,e] * W[d,e]
// y is fp16 (converted on LDS stage), W fp32, fp32 accumulate.
// ---------------------------------------------------------------------------
__global__ __launch_bounds__(256) void k_outproj(const __half* __restrict__ y,
                                                 const float* __restrict__ w,
                                                 float* __restrict__ out){
    __shared__ __align__(16) float As[16][68];
    __shared__ __align__(16) float Bs[16][68];
    __shared__ __align__(16) float Ot[64][68];
    const int K = DINNER;
    int m0 = blockIdx.x * 64;
    int n0 = blockIdx.y * 64;
    int tid = threadIdx.x;
    int trow = tid >> 4, tcol = tid & 15;
    int lr = tid >> 2;
    int lk = (tid & 3) << 2;
    float acc[4][4];
    #pragma unroll
    for (int i = 0; i < 4; i++)
        #pragma unroll
        for (int j = 0; j < 4; j++) acc[i][j] = 0.f;

    for (int k0 = 0; k0 < K; k0 += 16){
        const __half2* yp2 = (const __half2*)(y + (size_t)(m0 + lr) * K + k0 + lk);
        __half2 h01 = yp2[0], h23 = yp2[1];
        float2 f01 = __half22float2(h01), f23 = __half22float2(h23);
        float4 bv = *(const float4*)(w + (size_t)(n0 + lr) * K + k0 + lk);
        __syncthreads();
        As[lk][lr] = f01.x; As[lk + 1][lr] = f01.y; As[lk + 2][lr] = f23.x; As[lk + 3][lr] = f23.y;
        Bs[lk][lr] = bv.x;  Bs[lk + 1][lr] = bv.y;  Bs[lk + 2][lr] = bv.z;  Bs[lk + 3][lr] = bv.w;
        __syncthreads();
        #pragma unroll
        for (int kk = 0; kk < 16; kk++){
            float4 a  = *(const float4*)&As[kk][trow << 2];
            float4 bb = *(const float4*)&Bs[kk][tcol << 2];
            acc[0][0] = fmaf(a.x, bb.x, acc[0][0]); acc[0][1] = fmaf(a.x, bb.y, acc[0][1]);
            acc[0][2] = fmaf(a.x, bb.z, acc[0][2]); acc[0][3] = fmaf(a.x, bb.w, acc[0][3]);
            acc[1][0] = fmaf(a.y, bb.x, acc[1][0]); acc[1][1] = fmaf(a.y, bb.y, acc[1][1]);
            acc[1][2] = fmaf(a.y, bb.z, acc[1][2]); acc[1][3] = fmaf(a.y, bb.w, acc[1][3]);
            acc[2][0] = fmaf(a.z, bb.x, acc[2][0]); acc[2][1] = fmaf(a.z, bb.y, acc[2][1]);
            acc[2][2] = fmaf(a.z, bb.z, acc[2][2]); acc[2][3] = fmaf(a.z, bb.w, acc[2][3]);
            acc[3][0] = fmaf(a.w, bb.x, acc[3][0]); acc[3][1] = fmaf(a.w, bb.y, acc[3][1]);
            acc[3][2] = fmaf(a.w, bb.z, acc[3][2]); acc[3][3] = fmaf(a.w, bb.w, acc[3][3]);
        }
    }
    __syncthreads();
    #pragma unroll
    for (int i = 0; i < 4; i++)
        #pragma unroll
        for (int j = 0; j < 4; j++)
            Ot[(tcol << 2) + j][(trow << 2) + i] = acc[i][j];
    __syncthreads();
    int b  = m0 >> 11;
    int l0 = m0 & (LEN - 1);
    for (int v = tid; v < 4096; v += 256){
        int cl = v >> 6, rl = v & 63;
        out[(size_t)b * DMODEL * LEN + (size_t)(n0 + cl) * LEN + l0 + rl] = Ot[cl][rl];
    }
}

// ---------------------------------------------------------------------------
extern "C" void kernel_launch(void* const* d_in, const int* in_sizes, int n_in,
                              void* d_out, int out_size, void* d_ws, size_t ws_size,
                              hipStream_t stream) {
    const float* x          = (const float*)d_in[0];
    const float* proj_w     = (const float*)d_in[1];
    const float* in_proj_w  = (const float*)d_in[2];
    const float* conv_w     = (const float*)d_in[3];
    const float* conv_b     = (const float*)d_in[4];
    const float* dt_bias    = (const float*)d_in[5];
    const float* A_log      = (const float*)d_in[6];
    const float* D_skip     = (const float*)d_in[7];
    const float* norm_w     = (const float*)d_in[8];
    const float* out_proj_w = (const float*)d_in[9];
    float* out = (float*)d_out;

    // u (fp32, 2,097,152 floats == out_size) lives in d_out; dead before
    // k_outproj overwrites d_out with the final result.
    float* u = out;

    // Workspace: fp16 intermediates only. Total 42,467,328 bytes (~40.5 MiB).
    char* wsb = (char*)d_ws;
    __half* z_h   = (__half*)(wsb);                    // 8192*768  = 12,582,912 B
    __half* xbc_h = (__half*)(wsb + 12582912);         // 8192*800  = 13,107,200 B
    __half* y_h   = (__half*)(wsb + 25690112);         // 8192*768  = 12,582,912 B
    __half* dt_h  = (__half*)(wsb + 38273024);         // 8192*256  =  4,194,304 B

    k_convproj<<<256, 256, 0, stream>>>(x, proj_w, u);
    k_inproj  <<<dim3(128, 29), 256, 0, stream>>>(u, in_proj_w, dt_bias, z_h, xbc_h, dt_h);
    k_scan    <<<256, 64, 0, stream>>>(dt_h, xbc_h, conv_w, conv_b, A_log, D_skip, y_h);
    k_norm    <<<8192, 256, 0, stream>>>(y_h, z_h, norm_w);
    k_outproj <<<dim3(128, 4), 256, 0, stream>>>(y_h, out_proj_w, out);
}

// Round 3
// 568.949 us; speedup vs baseline: 2.1294x; 2.1294x over previous
//
#include <hip/hip_runtime.h>
#include <hip/hip_fp16.h>
#include <math.h>

// Problem constants
#define B_     4
#define CIN    128
#define LEN    2048
#define DMODEL 256
#define DSTATE 16
#define NHEADS 256
#define DINNER 768
#define CONVDIM 800      // DINNER + 2*DSTATE
#define DINPROJ 1824     // 2*DINNER + 2*DSTATE + NHEADS
#define EPS_   1e-5f
#define CHUNK  64
#define NCHUNK 32        // LEN / CHUNK

__device__ __forceinline__ float silu_(float x){ return x / (1.0f + __expf(-x)); }
__device__ __forceinline__ float softplus_(float x){
    return x > 0.f ? x + log1pf(__expf(-x)) : log1pf(__expf(x));
}

// ---------------------------------------------------------------------------
// Kernel 1: conv projection  x(B,CIN,L) * proj_w(DMODEL,CIN,4), pad (1,2)
// -> u stored as (B, L, DMODEL) fp32 (lives in d_out; dead before out_proj)
// ---------------------------------------------------------------------------
__global__ __launch_bounds__(256) void k_convproj(const float* __restrict__ x,
                                                  const float* __restrict__ w,
                                                  float* __restrict__ u){
    __shared__ float xs[CIN][36];
    int blk = blockIdx.x;              // 0..255
    int b  = blk >> 6;
    int l0 = (blk & 63) << 5;          // *32
    const float* xb = x + (size_t)b * CIN * LEN;
    for (int idx = threadIdx.x; idx < CIN * 35; idx += 256){
        int ci = idx / 35, j = idx % 35;
        int gl = l0 - 1 + j;
        float v = 0.f;
        if (gl >= 0 && gl < LEN) v = xb[ci * LEN + gl];
        xs[ci][j] = v;
    }
    __syncthreads();
    int d = threadIdx.x;
    float acc[32];
    #pragma unroll
    for (int i = 0; i < 32; i++) acc[i] = 0.f;
    const float* wd = w + (size_t)d * CIN * 4;
    for (int ci = 0; ci < CIN; ci++){
        float4 wv = *(const float4*)(wd + ci * 4);
        float xv[35];
        #pragma unroll
        for (int j = 0; j < 35; j++) xv[j] = xs[ci][j];
        #pragma unroll
        for (int l = 0; l < 32; l++){
            acc[l] = fmaf(xv[l],     wv.x, acc[l]);
            acc[l] = fmaf(xv[l + 1], wv.y, acc[l]);
            acc[l] = fmaf(xv[l + 2], wv.z, acc[l]);
            acc[l] = fmaf(xv[l + 3], wv.w, acc[l]);
        }
    }
    float* ub = u + ((size_t)(b * LEN + l0)) * DMODEL + d;
    #pragma unroll
    for (int l = 0; l < 32; l++) ub[(size_t)l * DMODEL] = acc[l];
}

// ---------------------------------------------------------------------------
// Kernel 2: in_proj GEMM  [M=8192, N=1824] = u[M,256] . W[1824,256]^T
// fp32 accumulate, fp16 stores: z (768), xbc (800), dt (256, softplus+bias).
// ---------------------------------------------------------------------------
__global__ __launch_bounds__(256) void k_inproj(const float* __restrict__ u,
                                                const float* __restrict__ w,
                                                const float* __restrict__ dt_bias,
                                                __half* __restrict__ z,
                                                __half* __restrict__ xbc,
                                                __half* __restrict__ dt){
    __shared__ __align__(16) float As[16][68];
    __shared__ __align__(16) float Bs[16][68];
    const int K = DMODEL;
    int m0 = blockIdx.x * 64;
    int n0 = blockIdx.y * 64;
    int tid = threadIdx.x;
    int trow = tid >> 4, tcol = tid & 15;
    int lr = tid >> 2;
    int lk = (tid & 3) << 2;
    float acc[4][4];
    #pragma unroll
    for (int i = 0; i < 4; i++)
        #pragma unroll
        for (int j = 0; j < 4; j++) acc[i][j] = 0.f;

    for (int k0 = 0; k0 < K; k0 += 16){
        float4 av = *(const float4*)(u + (size_t)(m0 + lr) * K + k0 + lk);
        int nrow = n0 + lr;
        float4 bv = make_float4(0.f, 0.f, 0.f, 0.f);
        if (nrow < DINPROJ) bv = *(const float4*)(w + (size_t)nrow * K + k0 + lk);
        __syncthreads();
        As[lk][lr] = av.x; As[lk + 1][lr] = av.y; As[lk + 2][lr] = av.z; As[lk + 3][lr] = av.w;
        Bs[lk][lr] = bv.x; Bs[lk + 1][lr] = bv.y; Bs[lk + 2][lr] = bv.z; Bs[lk + 3][lr] = bv.w;
        __syncthreads();
        #pragma unroll
        for (int kk = 0; kk < 16; kk++){
            float4 a  = *(const float4*)&As[kk][trow << 2];
            float4 bb = *(const float4*)&Bs[kk][tcol << 2];
            acc[0][0] = fmaf(a.x, bb.x, acc[0][0]); acc[0][1] = fmaf(a.x, bb.y, acc[0][1]);
            acc[0][2] = fmaf(a.x, bb.z, acc[0][2]); acc[0][3] = fmaf(a.x, bb.w, acc[0][3]);
            acc[1][0] = fmaf(a.y, bb.x, acc[1][0]); acc[1][1] = fmaf(a.y, bb.y, acc[1][1]);
            acc[1][2] = fmaf(a.y, bb.z, acc[1][2]); acc[1][3] = fmaf(a.y, bb.w, acc[1][3]);
            acc[2][0] = fmaf(a.z, bb.x, acc[2][0]); acc[2][1] = fmaf(a.z, bb.y, acc[2][1]);
            acc[2][2] = fmaf(a.z, bb.z, acc[2][2]); acc[2][3] = fmaf(a.z, bb.w, acc[2][3]);
            acc[3][0] = fmaf(a.w, bb.x, acc[3][0]); acc[3][1] = fmaf(a.w, bb.y, acc[3][1]);
            acc[3][2] = fmaf(a.w, bb.z, acc[3][2]); acc[3][3] = fmaf(a.w, bb.w, acc[3][3]);
        }
    }
    #pragma unroll
    for (int i = 0; i < 4; i++){
        int row = m0 + (trow << 2) + i;
        #pragma unroll
        for (int j = 0; j < 4; j++){
            int col = n0 + (tcol << 2) + j;
            if (col >= DINPROJ) continue;
            float v = acc[i][j];
            if (col < DINNER)                z[(size_t)row * DINNER + col] = __float2half(v);
            else if (col < DINNER + CONVDIM) xbc[(size_t)row * CONVDIM + (col - DINNER)] = __float2half(v);
            else {
                int hh = col - (DINNER + CONVDIM);
                dt[(size_t)row * NHEADS + hh] = __float2half(softplus_(v + dt_bias[hh]));
            }
        }
    }
}

// ---------------------------------------------------------------------------
// Kernel 3a (scan pass A): per (b, head-group, chunk) run the fused
// conv+silu+recurrence over CHUNK steps from zero state; emit the chunk-local
// final state (3x16 per head) and the chunk decay exp(A*sum(dt)).
// No C-channel work, no shuffles needed here.
// ---------------------------------------------------------------------------
__global__ __launch_bounds__(64) void k_scanA(const __half* __restrict__ dtb,
                                              const __half* __restrict__ xbc,
                                              const float* __restrict__ cw,
                                              const float* __restrict__ cb,
                                              const float* __restrict__ A_log,
                                              float* __restrict__ cstate,
                                              float* __restrict__ dsum){
    int blk = blockIdx.x;              // 0..8191
    int c  = blk & (NCHUNK - 1);
    int hg = (blk >> 5) & 63;
    int b  = blk >> 11;
    int lane = threadIdx.x;
    int hl = lane >> 4;
    int n  = lane & 15;
    int h  = hg * 4 + hl;
    int c0 = h * 3;
    float A = -__expf(A_log[h]);
    float4 wx0 = *(const float4*)(cw + (size_t)(c0 + 0) * 4);
    float4 wx1 = *(const float4*)(cw + (size_t)(c0 + 1) * 4);
    float4 wx2 = *(const float4*)(cw + (size_t)(c0 + 2) * 4);
    float4 wBv = *(const float4*)(cw + (size_t)(DINNER + n) * 4);
    float bx0 = cb[c0], bx1 = cb[c0 + 1], bx2 = cb[c0 + 2];
    float bBv = cb[DINNER + n];

    int t0 = c * CHUNK;
    const __half* xrow = xbc + (size_t)b * LEN * CONVDIM;
    const __half* dtp  = dtb + ((size_t)b * LEN + t0) * NHEADS + h;
    // init conv windows from the 3 rows before the chunk (zeros = causal pad)
    #define LDROW(t, ch) (((t) >= 0) ? __half2float(xrow[(size_t)(t) * CONVDIM + (ch)]) : 0.f)
    float r0a = LDROW(t0-3, c0),   r0b = LDROW(t0-2, c0),   r0c = LDROW(t0-1, c0);
    float r1a = LDROW(t0-3, c0+1), r1b = LDROW(t0-2, c0+1), r1c = LDROW(t0-1, c0+1);
    float r2a = LDROW(t0-3, c0+2), r2b = LDROW(t0-2, c0+2), r2c = LDROW(t0-1, c0+2);
    float rBa = LDROW(t0-3, DINNER+n), rBb = LDROW(t0-2, DINNER+n), rBc = LDROW(t0-1, DINNER+n);

    float h0 = 0.f, h1 = 0.f, h2 = 0.f, sdt = 0.f;
    const __half* xr = xrow + (size_t)t0 * CONVDIM;
    for (int t = 0; t < CHUNK; t++){
        float cx0 = __half2float(xr[c0]);
        float cx1 = __half2float(xr[c0 + 1]);
        float cx2 = __half2float(xr[c0 + 2]);
        float cB  = __half2float(xr[DINNER + n]);
        float cdt = __half2float(dtp[(size_t)t * NHEADS]);
        float vx0 = silu_(bx0 + r0a * wx0.x + r0b * wx0.y + r0c * wx0.z + cx0 * wx0.w);
        float vx1 = silu_(bx1 + r1a * wx1.x + r1b * wx1.y + r1c * wx1.z + cx1 * wx1.w);
        float vx2 = silu_(bx2 + r2a * wx2.x + r2b * wx2.y + r2c * wx2.z + cx2 * wx2.w);
        float vB  = silu_(bBv + rBa * wBv.x + rBb * wBv.y + rBc * wBv.z + cB * wBv.w);
        r0a = r0b; r0b = r0c; r0c = cx0;
        r1a = r1b; r1b = r1c; r1c = cx1;
        r2a = r2b; r2b = r2c; r2c = cx2;
        rBa = rBb; rBb = rBc; rBc = cB;
        float dA  = __expf(cdt * A);
        float dtB = cdt * vB;
        h0 = fmaf(h0, dA, vx0 * dtB);
        h1 = fmaf(h1, dA, vx1 * dtB);
        h2 = fmaf(h2, dA, vx2 * dtB);
        sdt += cdt;
        xr += CONVDIM;
    }
    size_t sbase = (((size_t)(b * NHEADS + h)) * NCHUNK + c) * 48;
    cstate[sbase + n]      = h0;
    cstate[sbase + 16 + n] = h1;
    cstate[sbase + 32 + n] = h2;
    if (n == 0) dsum[(size_t)(b * NHEADS + h) * NCHUNK + c] = __expf(A * sdt);
}

// ---------------------------------------------------------------------------
// Kernel 3b (scan pass B): per (b,h), sequentially combine the 32 chunk
// summaries; overwrite cstate[c] in place with the INITIAL state of chunk c.
// ---------------------------------------------------------------------------
__global__ __launch_bounds__(64) void k_scanB(float* __restrict__ cstate,
                                              const float* __restrict__ dsum){
    int bh = blockIdx.x;               // 0..1023
    int lane = threadIdx.x;
    if (lane >= 48) return;
    float* st = cstate + (size_t)bh * NCHUNK * 48 + lane;
    const float* dd = dsum + (size_t)bh * NCHUNK;
    float H = 0.f;
    for (int c = 0; c < NCHUNK; c++){
        float d = dd[c];
        float s = st[(size_t)c * 48];
        st[(size_t)c * 48] = H;
        H = fmaf(H, d, s);
    }
}

// ---------------------------------------------------------------------------
// Kernel 3c (scan pass C): per (b, head-group, chunk) re-run the fused
// conv+silu+recurrence over CHUNK steps starting from the correct initial
// state; reduce over n via shfl and write y (+ D_skip*x).
// ---------------------------------------------------------------------------
__global__ __launch_bounds__(64) void k_scanC(const __half* __restrict__ dtb,
                                              const __half* __restrict__ xbc,
                                              const float* __restrict__ cw,
                                              const float* __restrict__ cb,
                                              const float* __restrict__ A_log,
                                              const float* __restrict__ D_skip,
                                              const float* __restrict__ cstate,
                                              __half* __restrict__ y){
    int blk = blockIdx.x;              // 0..8191
    int c  = blk & (NCHUNK - 1);
    int hg = (blk >> 5) & 63;
    int b  = blk >> 11;
    int lane = threadIdx.x;
    int hl = lane >> 4;
    int n  = lane & 15;
    int h  = hg * 4 + hl;
    int c0 = h * 3;
    float A   = -__expf(A_log[h]);
    float Dsk = D_skip[h];
    float4 wx0 = *(const float4*)(cw + (size_t)(c0 + 0) * 4);
    float4 wx1 = *(const float4*)(cw + (size_t)(c0 + 1) * 4);
    float4 wx2 = *(const float4*)(cw + (size_t)(c0 + 2) * 4);
    float4 wBv = *(const float4*)(cw + (size_t)(DINNER + n) * 4);
    float4 wCv = *(const float4*)(cw + (size_t)(DINNER + DSTATE + n) * 4);
    float bx0 = cb[c0], bx1 = cb[c0 + 1], bx2 = cb[c0 + 2];
    float bBv = cb[DINNER + n], bCv = cb[DINNER + DSTATE + n];

    int t0 = c * CHUNK;
    const __half* xrow = xbc + (size_t)b * LEN * CONVDIM;
    const __half* dtp  = dtb + ((size_t)b * LEN + t0) * NHEADS + h;
    float r0a = LDROW(t0-3, c0),   r0b = LDROW(t0-2, c0),   r0c = LDROW(t0-1, c0);
    float r1a = LDROW(t0-3, c0+1), r1b = LDROW(t0-2, c0+1), r1c = LDROW(t0-1, c0+1);
    float r2a = LDROW(t0-3, c0+2), r2b = LDROW(t0-2, c0+2), r2c = LDROW(t0-1, c0+2);
    float rBa = LDROW(t0-3, DINNER+n), rBb = LDROW(t0-2, DINNER+n), rBc = LDROW(t0-1, DINNER+n);
    float rCa = LDROW(t0-3, DINNER+DSTATE+n), rCb = LDROW(t0-2, DINNER+DSTATE+n), rCc = LDROW(t0-1, DINNER+DSTATE+n);

    size_t sbase = (((size_t)(b * NHEADS + h)) * NCHUNK + c) * 48;
    float h0 = cstate[sbase + n];
    float h1 = cstate[sbase + 16 + n];
    float h2 = cstate[sbase + 32 + n];

    const __half* xr = xrow + (size_t)t0 * CONVDIM;
    __half* yp = y + ((size_t)b * LEN + t0) * DINNER + c0;
    for (int t = 0; t < CHUNK; t++){
        float cx0 = __half2float(xr[c0]);
        float cx1 = __half2float(xr[c0 + 1]);
        float cx2 = __half2float(xr[c0 + 2]);
        float cB  = __half2float(xr[DINNER + n]);
        float cC  = __half2float(xr[DINNER + DSTATE + n]);
        float cdt = __half2float(dtp[(size_t)t * NHEADS]);
        float vx0 = silu_(bx0 + r0a * wx0.x + r0b * wx0.y + r0c * wx0.z + cx0 * wx0.w);
        float vx1 = silu_(bx1 + r1a * wx1.x + r1b * wx1.y + r1c * wx1.z + cx1 * wx1.w);
        float vx2 = silu_(bx2 + r2a * wx2.x + r2b * wx2.y + r2c * wx2.z + cx2 * wx2.w);
        float vB  = silu_(bBv + rBa * wBv.x + rBb * wBv.y + rBc * wBv.z + cB * wBv.w);
        float vC  = silu_(bCv + rCa * wCv.x + rCb * wCv.y + rCc * wCv.z + cC * wCv.w);
        r0a = r0b; r0b = r0c; r0c = cx0;
        r1a = r1b; r1b = r1c; r1c = cx1;
        r2a = r2b; r2b = r2c; r2c = cx2;
        rBa = rBb; rBb = rBc; rBc = cB;
        rCa = rCb; rCb = rCc; rCc = cC;
        float dA  = __expf(cdt * A);
        float dtB = cdt * vB;
        h0 = fmaf(h0, dA, vx0 * dtB);
        h1 = fmaf(h1, dA, vx1 * dtB);
        h2 = fmaf(h2, dA, vx2 * dtB);
        float p0 = h0 * vC, p1 = h1 * vC, p2 = h2 * vC;
        #pragma unroll
        for (int m = 1; m < 16; m <<= 1){
            p0 += __shfl_xor(p0, m, 64);
            p1 += __shfl_xor(p1, m, 64);
            p2 += __shfl_xor(p2, m, 64);
        }
        if (n < 3){
            float pv = (n == 0) ? p0 : ((n == 1) ? p1 : p2);
            float xv = (n == 0) ? vx0 : ((n == 1) ? vx1 : vx2);
            yp[n] = __float2half(fmaf(Dsk, xv, pv));
        }
        xr += CONVDIM;
        yp += DINNER;
    }
}

// ---------------------------------------------------------------------------
// Kernel 4: gated RMSNorm (in place on y, fp16 storage, fp32 math)
// ---------------------------------------------------------------------------
__global__ __launch_bounds__(256) void k_norm(__half* __restrict__ y,
                                              const __half* __restrict__ z,
                                              const float* __restrict__ nw){
    __shared__ float wsum[4];
    size_t r = blockIdx.x;
    int tid = threadIdx.x;
    const __half* zr = z + r * DINNER;
    __half* yr = y + r * DINNER;
    int e0 = tid, e1 = tid + 256, e2 = tid + 512;
    float t0 = __half2float(yr[e0]) * silu_(__half2float(zr[e0]));
    float t1 = __half2float(yr[e1]) * silu_(__half2float(zr[e1]));
    float t2 = __half2float(yr[e2]) * silu_(__half2float(zr[e2]));
    float ss = t0 * t0 + t1 * t1 + t2 * t2;
    #pragma unroll
    for (int m = 1; m < 64; m <<= 1) ss += __shfl_xor(ss, m, 64);
    if ((tid & 63) == 0) wsum[tid >> 6] = ss;
    __syncthreads();
    float tot = wsum[0] + wsum[1] + wsum[2] + wsum[3];
    float sc = rsqrtf(tot / (float)DINNER + EPS_);
    yr[e0] = __float2half(t0 * sc * nw[e0]);
    yr[e1] = __float2half(t1 * sc * nw[e1]);
    yr[e2] = __float2half(t2 * sc * nw[e2]);
}

// ---------------------------------------------------------------------------
// Kernel 5: out_proj GEMM  out[b,d,l] = sum_e y[b,l,e] * W[d,e]
// ---------------------------------------------------------------------------
__global__ __launch_bounds__(256) void k_outproj(const __half* __restrict__ y,
                                                 const float* __restrict__ w,
                                                 float* __restrict__ out){
    __shared__ __align__(16) float As[16][68];
    __shared__ __align__(16) float Bs[16][68];
    __shared__ __align__(16) float Ot[64][68];
    const int K = DINNER;
    int m0 = blockIdx.x * 64;
    int n0 = blockIdx.y * 64;
    int tid = threadIdx.x;
    int trow = tid >> 4, tcol = tid & 15;
    int lr = tid >> 2;
    int lk = (tid & 3) << 2;
    float acc[4][4];
    #pragma unroll
    for (int i = 0; i < 4; i++)
        #pragma unroll
        for (int j = 0; j < 4; j++) acc[i][j] = 0.f;

    for (int k0 = 0; k0 < K; k0 += 16){
        const __half2* yp2 = (const __half2*)(y + (size_t)(m0 + lr) * K + k0 + lk);
        __half2 h01 = yp2[0], h23 = yp2[1];
        float2 f01 = __half22float2(h01), f23 = __half22float2(h23);
        float4 bv = *(const float4*)(w + (size_t)(n0 + lr) * K + k0 + lk);
        __syncthreads();
        As[lk][lr] = f01.x; As[lk + 1][lr] = f01.y; As[lk + 2][lr] = f23.x; As[lk + 3][lr] = f23.y;
        Bs[lk][lr] = bv.x;  Bs[lk + 1][lr] = bv.y;  Bs[lk + 2][lr] = bv.z;  Bs[lk + 3][lr] = bv.w;
        __syncthreads();
        #pragma unroll
        for (int kk = 0; kk < 16; kk++){
            float4 a  = *(const float4*)&As[kk][trow << 2];
            float4 bb = *(const float4*)&Bs[kk][tcol << 2];
            acc[0][0] = fmaf(a.x, bb.x, acc[0][0]); acc[0][1] = fmaf(a.x, bb.y, acc[0][1]);
            acc[0][2] = fmaf(a.x, bb.z, acc[0][2]); acc[0][3] = fmaf(a.x, bb.w, acc[0][3]);
            acc[1][0] = fmaf(a.y, bb.x, acc[1][0]); acc[1][1] = fmaf(a.y, bb.y, acc[1][1]);
            acc[1][2] = fmaf(a.y, bb.z, acc[1][2]); acc[1][3] = fmaf(a.y, bb.w, acc[1][3]);
            acc[2][0] = fmaf(a.z, bb.x, acc[2][0]); acc[2][1] = fmaf(a.z, bb.y, acc[2][1]);
            acc[2][2] = fmaf(a.z, bb.z, acc[2][2]); acc[2][3] = fmaf(a.z, bb.w, acc[2][3]);
            acc[3][0] = fmaf(a.w, bb.x, acc[3][0]); acc[3][1] = fmaf(a.w, bb.y, acc[3][1]);
            acc[3][2] = fmaf(a.w, bb.z, acc[3][2]); acc[3][3] = fmaf(a.w, bb.w, acc[3][3]);
        }
    }
    __syncthreads();
    #pragma unroll
    for (int i = 0; i < 4; i++)
        #pragma unroll
        for (int j = 0; j < 4; j++)
            Ot[(tcol << 2) + j][(trow << 2) + i] = acc[i][j];
    __syncthreads();
    int b  = m0 >> 11;
    int l0 = m0 & (LEN - 1);
    for (int v = tid; v < 4096; v += 256){
        int cl = v >> 6, rl = v & 63;
        out[(size_t)b * DMODEL * LEN + (size_t)(n0 + cl) * LEN + l0 + rl] = Ot[cl][rl];
    }
}

// ---------------------------------------------------------------------------
extern "C" void kernel_launch(void* const* d_in, const int* in_sizes, int n_in,
                              void* d_out, int out_size, void* d_ws, size_t ws_size,
                              hipStream_t stream) {
    const float* x          = (const float*)d_in[0];
    const float* proj_w     = (const float*)d_in[1];
    const float* in_proj_w  = (const float*)d_in[2];
    const float* conv_w     = (const float*)d_in[3];
    const float* conv_b     = (const float*)d_in[4];
    const float* dt_bias    = (const float*)d_in[5];
    const float* A_log      = (const float*)d_in[6];
    const float* D_skip     = (const float*)d_in[7];
    const float* norm_w     = (const float*)d_in[8];
    const float* out_proj_w = (const float*)d_in[9];
    float* out = (float*)d_out;

    // u (fp32, == out_size) lives in d_out; dead before k_outproj writes out.
    float* u = out;

    // Workspace layout (bytes), total 48,889,856 (~46.6 MiB):
    char* wsb = (char*)d_ws;
    __half* z_h    = (__half*)(wsb);                   // 12,582,912
    __half* xbc_h  = (__half*)(wsb + 12582912);        // 13,107,200
    __half* y_h    = (__half*)(wsb + 25690112);        // 12,582,912
    __half* dt_h   = (__half*)(wsb + 38273024);        //  4,194,304
    float*  cstate = (float*)(wsb + 42467328);         //  6,291,456 (B*NH*NCHUNK*48)
    float*  dsum   = (float*)(wsb + 48758784);         //    131,072 (B*NH*NCHUNK)

    k_convproj<<<256, 256, 0, stream>>>(x, proj_w, u);
    k_inproj  <<<dim3(128, 29), 256, 0, stream>>>(u, in_proj_w, dt_bias, z_h, xbc_h, dt_h);
    k_scanA   <<<8192, 64, 0, stream>>>(dt_h, xbc_h, conv_w, conv_b, A_log, cstate, dsum);
    k_scanB   <<<1024, 64, 0, stream>>>(cstate, dsum);
    k_scanC   <<<8192, 64, 0, stream>>>(dt_h, xbc_h, conv_w, conv_b, A_log, D_skip, cstate, y_h);
    k_norm    <<<8192, 256, 0, stream>>>(y_h, z_h, norm_w);
    k_outproj <<<dim3(128, 4), 256, 0, stream>>>(y_h, out_proj_w, out);
}

// Round 4
// 433.343 us; speedup vs baseline: 2.7957x; 1.3129x over previous
//
#include <hip/hip_runtime.h>
#include <hip/hip_fp16.h>
#include <math.h>

// Problem constants
#define B_     4
#define CIN    128
#define LEN    2048
#define DMODEL 256
#define DSTATE 16
#define NHEADS 256
#define DINNER 768
#define CONVDIM 800      // DINNER + 2*DSTATE
#define DINPROJ 1824     // 2*DINNER + 2*DSTATE + NHEADS
#define EPS_   1e-5f
#define CHUNK  64
#define NCHUNK 32        // LEN / CHUNK

__device__ __forceinline__ float silu_(float x){ return x / (1.0f + __expf(-x)); }
__device__ __forceinline__ float softplus_(float x){
    return x > 0.f ? x + log1pf(__expf(-x)) : log1pf(__expf(x));
}

// ---------------------------------------------------------------------------
// Kernel 1: conv projection  x(B,CIN,L) * proj_w(DMODEL,CIN,4), pad (1,2)
// -> u stored as (B, L, DMODEL) fp32 (lives in d_out; dead before out_proj)
// ---------------------------------------------------------------------------
__global__ __launch_bounds__(256) void k_convproj(const float* __restrict__ x,
                                                  const float* __restrict__ w,
                                                  float* __restrict__ u){
    __shared__ float xs[CIN][36];
    int blk = blockIdx.x;              // 0..255
    int b  = blk >> 6;
    int l0 = (blk & 63) << 5;          // *32
    const float* xb = x + (size_t)b * CIN * LEN;
    for (int idx = threadIdx.x; idx < CIN * 35; idx += 256){
        int ci = idx / 35, j = idx % 35;
        int gl = l0 - 1 + j;
        float v = 0.f;
        if (gl >= 0 && gl < LEN) v = xb[ci * LEN + gl];
        xs[ci][j] = v;
    }
    __syncthreads();
    int d = threadIdx.x;
    float acc[32];
    #pragma unroll
    for (int i = 0; i < 32; i++) acc[i] = 0.f;
    const float* wd = w + (size_t)d * CIN * 4;
    for (int ci = 0; ci < CIN; ci++){
        float4 wv = *(const float4*)(wd + ci * 4);
        float xv[35];
        #pragma unroll
        for (int j = 0; j < 35; j++) xv[j] = xs[ci][j];
        #pragma unroll
        for (int l = 0; l < 32; l++){
            acc[l] = fmaf(xv[l],     wv.x, acc[l]);
            acc[l] = fmaf(xv[l + 1], wv.y, acc[l]);
            acc[l] = fmaf(xv[l + 2], wv.z, acc[l]);
            acc[l] = fmaf(xv[l + 3], wv.w, acc[l]);
        }
    }
    float* ub = u + ((size_t)(b * LEN + l0)) * DMODEL + d;
    #pragma unroll
    for (int l = 0; l < 32; l++) ub[(size_t)l * DMODEL] = acc[l];
}

// ---------------------------------------------------------------------------
// Kernel 2: in_proj GEMM  [M=8192, N=1824] = u[M,256] . W[1824,256]^T
// fp32 accumulate, fp16 stores: z (768), xbc (800), dt (256, softplus+bias).
// ---------------------------------------------------------------------------
__global__ __launch_bounds__(256) void k_inproj(const float* __restrict__ u,
                                                const float* __restrict__ w,
                                                const float* __restrict__ dt_bias,
                                                __half* __restrict__ z,
                                                __half* __restrict__ xbc,
                                                __half* __restrict__ dt){
    __shared__ __align__(16) float As[16][68];
    __shared__ __align__(16) float Bs[16][68];
    const int K = DMODEL;
    int m0 = blockIdx.x * 64;
    int n0 = blockIdx.y * 64;
    int tid = threadIdx.x;
    int trow = tid >> 4, tcol = tid & 15;
    int lr = tid >> 2;
    int lk = (tid & 3) << 2;
    float acc[4][4];
    #pragma unroll
    for (int i = 0; i < 4; i++)
        #pragma unroll
        for (int j = 0; j < 4; j++) acc[i][j] = 0.f;

    for (int k0 = 0; k0 < K; k0 += 16){
        float4 av = *(const float4*)(u + (size_t)(m0 + lr) * K + k0 + lk);
        int nrow = n0 + lr;
        float4 bv = make_float4(0.f, 0.f, 0.f, 0.f);
        if (nrow < DINPROJ) bv = *(const float4*)(w + (size_t)nrow * K + k0 + lk);
        __syncthreads();
        As[lk][lr] = av.x; As[lk + 1][lr] = av.y; As[lk + 2][lr] = av.z; As[lk + 3][lr] = av.w;
        Bs[lk][lr] = bv.x; Bs[lk + 1][lr] = bv.y; Bs[lk + 2][lr] = bv.z; Bs[lk + 3][lr] = bv.w;
        __syncthreads();
        #pragma unroll
        for (int kk = 0; kk < 16; kk++){
            float4 a  = *(const float4*)&As[kk][trow << 2];
            float4 bb = *(const float4*)&Bs[kk][tcol << 2];
            acc[0][0] = fmaf(a.x, bb.x, acc[0][0]); acc[0][1] = fmaf(a.x, bb.y, acc[0][1]);
            acc[0][2] = fmaf(a.x, bb.z, acc[0][2]); acc[0][3] = fmaf(a.x, bb.w, acc[0][3]);
            acc[1][0] = fmaf(a.y, bb.x, acc[1][0]); acc[1][1] = fmaf(a.y, bb.y, acc[1][1]);
            acc[1][2] = fmaf(a.y, bb.z, acc[1][2]); acc[1][3] = fmaf(a.y, bb.w, acc[1][3]);
            acc[2][0] = fmaf(a.z, bb.x, acc[2][0]); acc[2][1] = fmaf(a.z, bb.y, acc[2][1]);
            acc[2][2] = fmaf(a.z, bb.z, acc[2][2]); acc[2][3] = fmaf(a.z, bb.w, acc[2][3]);
            acc[3][0] = fmaf(a.w, bb.x, acc[3][0]); acc[3][1] = fmaf(a.w, bb.y, acc[3][1]);
            acc[3][2] = fmaf(a.w, bb.z, acc[3][2]); acc[3][3] = fmaf(a.w, bb.w, acc[3][3]);
        }
    }
    #pragma unroll
    for (int i = 0; i < 4; i++){
        int row = m0 + (trow << 2) + i;
        #pragma unroll
        for (int j = 0; j < 4; j++){
            int col = n0 + (tcol << 2) + j;
            if (col >= DINPROJ) continue;
            float v = acc[i][j];
            if (col < DINNER)                z[(size_t)row * DINNER + col] = __float2half(v);
            else if (col < DINNER + CONVDIM) xbc[(size_t)row * CONVDIM + (col - DINNER)] = __float2half(v);
            else {
                int hh = col - (DINNER + CONVDIM);
                dt[(size_t)row * NHEADS + hh] = __float2half(softplus_(v + dt_bias[hh]));
            }
        }
    }
}

// ---------------------------------------------------------------------------
// Kernel 3: depthwise causal conv (4-tap) + bias + SiLU, fp16 in/out.
// xcc[r,c] = silu(sum_k xbc[r-3+k,c]*cw[c,k] + cb[c])
// ---------------------------------------------------------------------------
__global__ __launch_bounds__(256) void k_dwconv(const __half* __restrict__ xbc,
                                                const float* __restrict__ cw,
                                                const float* __restrict__ cb,
                                                __half* __restrict__ xcc){
    int idx = blockIdx.x * 256 + threadIdx.x;   // < 8192*800
    int c = idx % CONVDIM;
    int r = idx / CONVDIM;
    int l = r & (LEN - 1);
    float4 wv = *(const float4*)(cw + c * 4);
    float acc = cb[c];
    if (l >= 3){
        const __half* base = xbc + (size_t)(r - 3) * CONVDIM + c;
        acc += __half2float(base[0]) * wv.x + __half2float(base[CONVDIM]) * wv.y +
               __half2float(base[2 * CONVDIM]) * wv.z + __half2float(base[3 * CONVDIM]) * wv.w;
    } else {
        const float wk[4] = {wv.x, wv.y, wv.z, wv.w};
        for (int k = 0; k < 4; k++){
            int t = l - 3 + k;
            if (t >= 0) acc += __half2float(xbc[(size_t)(r + k - 3) * CONVDIM + c]) * wk[k];
        }
    }
    xcc[idx] = __float2half(silu_(acc));
}

// ---------------------------------------------------------------------------
// Kernel 4a (scan pass A): per (b, head-group, chunk): pure recurrence over
// CHUNK steps from zero state on the precomputed xcc; emit final local state
// (fp16) and chunk decay exp(A*sum(dt)).
// ---------------------------------------------------------------------------
__global__ __launch_bounds__(64) void k_scanA(const __half* __restrict__ dtb,
                                              const __half* __restrict__ xcc,
                                              const float* __restrict__ A_log,
                                              __half* __restrict__ cstate,
                                              float* __restrict__ dsum){
    int blk = blockIdx.x;              // 0..8191
    int c  = blk & (NCHUNK - 1);
    int hg = (blk >> 5) & 63;
    int b  = blk >> 11;
    int lane = threadIdx.x;
    int hl = lane >> 4;
    int n  = lane & 15;
    int h  = hg * 4 + hl;
    int c0 = h * 3;
    float A = -__expf(A_log[h]);
    int t0 = c * CHUNK;
    const __half* xr  = xcc + ((size_t)b * LEN + t0) * CONVDIM;
    const __half* dtp = dtb + ((size_t)b * LEN + t0) * NHEADS + h;
    float h0 = 0.f, h1 = 0.f, h2 = 0.f, sdt = 0.f;
    for (int t = 0; t < CHUNK; t++){
        float vx0 = __half2float(xr[c0]);
        float vx1 = __half2float(xr[c0 + 1]);
        float vx2 = __half2float(xr[c0 + 2]);
        float vB  = __half2float(xr[DINNER + n]);
        float cdt = __half2float(dtp[(size_t)t * NHEADS]);
        float dA  = __expf(cdt * A);
        float dtB = cdt * vB;
        h0 = fmaf(h0, dA, vx0 * dtB);
        h1 = fmaf(h1, dA, vx1 * dtB);
        h2 = fmaf(h2, dA, vx2 * dtB);
        sdt += cdt;
        xr += CONVDIM;
    }
    size_t sbase = (((size_t)(b * NHEADS + h)) * NCHUNK + c) * 48;
    cstate[sbase + n]      = __float2half(h0);
    cstate[sbase + 16 + n] = __float2half(h1);
    cstate[sbase + 32 + n] = __float2half(h2);
    if (n == 0) dsum[(size_t)(b * NHEADS + h) * NCHUNK + c] = __expf(A * sdt);
}

// ---------------------------------------------------------------------------
// Kernel 4b (scan pass B): per (b,h), sequentially combine the 32 chunk
// summaries; overwrite cstate[c] in place with the INITIAL state of chunk c.
// ---------------------------------------------------------------------------
__global__ __launch_bounds__(64) void k_scanB(__half* __restrict__ cstate,
                                              const float* __restrict__ dsum){
    int bh = blockIdx.x;               // 0..1023
    int lane = threadIdx.x;
    if (lane >= 48) return;
    __half* st = cstate + (size_t)bh * NCHUNK * 48 + lane;
    const float* dd = dsum + (size_t)bh * NCHUNK;
    float H = 0.f;
    for (int c = 0; c < NCHUNK; c++){
        float d = dd[c];
        float s = __half2float(st[(size_t)c * 48]);
        st[(size_t)c * 48] = __float2half(H);
        H = fmaf(H, d, s);
    }
}

// ---------------------------------------------------------------------------
// Kernel 4c (scan pass C): per (b, head-group, chunk): recurrence from the
// correct initial state; y_p = reduce_n(h_p*C_n) via shfl; + D_skip*x.
// ---------------------------------------------------------------------------
__global__ __launch_bounds__(64) void k_scanC(const __half* __restrict__ dtb,
                                              const __half* __restrict__ xcc,
                                              const float* __restrict__ A_log,
                                              const float* __restrict__ D_skip,
                                              const __half* __restrict__ cstate,
                                              __half* __restrict__ y){
    int blk = blockIdx.x;              // 0..8191
    int c  = blk & (NCHUNK - 1);
    int hg = (blk >> 5) & 63;
    int b  = blk >> 11;
    int lane = threadIdx.x;
    int hl = lane >> 4;
    int n  = lane & 15;
    int h  = hg * 4 + hl;
    int c0 = h * 3;
    float A   = -__expf(A_log[h]);
    float Dsk = D_skip[h];
    int t0 = c * CHUNK;
    const __half* xr  = xcc + ((size_t)b * LEN + t0) * CONVDIM;
    const __half* dtp = dtb + ((size_t)b * LEN + t0) * NHEADS + h;
    size_t sbase = (((size_t)(b * NHEADS + h)) * NCHUNK + c) * 48;
    float h0 = __half2float(cstate[sbase + n]);
    float h1 = __half2float(cstate[sbase + 16 + n]);
    float h2 = __half2float(cstate[sbase + 32 + n]);
    __half* yp = y + ((size_t)b * LEN + t0) * DINNER + c0;
    for (int t = 0; t < CHUNK; t++){
        float vx0 = __half2float(xr[c0]);
        float vx1 = __half2float(xr[c0 + 1]);
        float vx2 = __half2float(xr[c0 + 2]);
        float vB  = __half2float(xr[DINNER + n]);
        float vC  = __half2float(xr[DINNER + DSTATE + n]);
        float cdt = __half2float(dtp[(size_t)t * NHEADS]);
        float dA  = __expf(cdt * A);
        float dtB = cdt * vB;
        h0 = fmaf(h0, dA, vx0 * dtB);
        h1 = fmaf(h1, dA, vx1 * dtB);
        h2 = fmaf(h2, dA, vx2 * dtB);
        float p0 = h0 * vC, p1 = h1 * vC, p2 = h2 * vC;
        #pragma unroll
        for (int m = 1; m < 16; m <<= 1){
            p0 += __shfl_xor(p0, m, 64);
            p1 += __shfl_xor(p1, m, 64);
            p2 += __shfl_xor(p2, m, 64);
        }
        if (n < 3){
            float pv = (n == 0) ? p0 : ((n == 1) ? p1 : p2);
            float xv = (n == 0) ? vx0 : ((n == 1) ? vx1 : vx2);
            yp[n] = __float2half(fmaf(Dsk, xv, pv));
        }
        xr += CONVDIM;
        yp += DINNER;
    }
}

// ---------------------------------------------------------------------------
// Kernel 5: gated RMSNorm (in place on y, fp16 storage, fp32 math)
// ---------------------------------------------------------------------------
__global__ __launch_bounds__(256) void k_norm(__half* __restrict__ y,
                                              const __half* __restrict__ z,
                                              const float* __restrict__ nw){
    __shared__ float wsum[4];
    size_t r = blockIdx.x;
    int tid = threadIdx.x;
    const __half* zr = z + r * DINNER;
    __half* yr = y + r * DINNER;
    int e0 = tid, e1 = tid + 256, e2 = tid + 512;
    float t0 = __half2float(yr[e0]) * silu_(__half2float(zr[e0]));
    float t1 = __half2float(yr[e1]) * silu_(__half2float(zr[e1]));
    float t2 = __half2float(yr[e2]) * silu_(__half2float(zr[e2]));
    float ss = t0 * t0 + t1 * t1 + t2 * t2;
    #pragma unroll
    for (int m = 1; m < 64; m <<= 1) ss += __shfl_xor(ss, m, 64);
    if ((tid & 63) == 0) wsum[tid >> 6] = ss;
    __syncthreads();
    float tot = wsum[0] + wsum[1] + wsum[2] + wsum[3];
    float sc = rsqrtf(tot / (float)DINNER + EPS_);
    yr[e0] = __float2half(t0 * sc * nw[e0]);
    yr[e1] = __float2half(t1 * sc * nw[e1]);
    yr[e2] = __float2half(t2 * sc * nw[e2]);
}

// ---------------------------------------------------------------------------
// Kernel 6: out_proj GEMM  out[b,d,l] = sum_e y[b,l,e] * W[d,e]
// ---------------------------------------------------------------------------
__global__ __launch_bounds__(256) void k_outproj(const __half* __restrict__ y,
                                                 const float* __restrict__ w,
                                                 float* __restrict__ out){
    __shared__ __align__(16) float As[16][68];
    __shared__ __align__(16) float Bs[16][68];
    __shared__ __align__(16) float Ot[64][68];
    const int K = DINNER;
    int m0 = blockIdx.x * 64;
    int n0 = blockIdx.y * 64;
    int tid = threadIdx.x;
    int trow = tid >> 4, tcol = tid & 15;
    int lr = tid >> 2;
    int lk = (tid & 3) << 2;
    float acc[4][4];
    #pragma unroll
    for (int i = 0; i < 4; i++)
        #pragma unroll
        for (int j = 0; j < 4; j++) acc[i][j] = 0.f;

    for (int k0 = 0; k0 < K; k0 += 16){
        const __half2* yp2 = (const __half2*)(y + (size_t)(m0 + lr) * K + k0 + lk);
        __half2 h01 = yp2[0], h23 = yp2[1];
        float2 f01 = __half22float2(h01), f23 = __half22float2(h23);
        float4 bv = *(const float4*)(w + (size_t)(n0 + lr) * K + k0 + lk);
        __syncthreads();
        As[lk][lr] = f01.x; As[lk + 1][lr] = f01.y; As[lk + 2][lr] = f23.x; As[lk + 3][lr] = f23.y;
        Bs[lk][lr] = bv.x;  Bs[lk + 1][lr] = bv.y;  Bs[lk + 2][lr] = bv.z;  Bs[lk + 3][lr] = bv.w;
        __syncthreads();
        #pragma unroll
        for (int kk = 0; kk < 16; kk++){
            float4 a  = *(const float4*)&As[kk][trow << 2];
            float4 bb = *(const float4*)&Bs[kk][tcol << 2];
            acc[0][0] = fmaf(a.x, bb.x, acc[0][0]); acc[0][1] = fmaf(a.x, bb.y, acc[0][1]);
            acc[0][2] = fmaf(a.x, bb.z, acc[0][2]); acc[0][3] = fmaf(a.x, bb.w, acc[0][3]);
            acc[1][0] = fmaf(a.y, bb.x, acc[1][0]); acc[1][1] = fmaf(a.y, bb.y, acc[1][1]);
            acc[1][2] = fmaf(a.y, bb.z, acc[1][2]); acc[1][3] = fmaf(a.y, bb.w, acc[1][3]);
            acc[2][0] = fmaf(a.z, bb.x, acc[2][0]); acc[2][1] = fmaf(a.z, bb.y, acc[2][1]);
            acc[2][2] = fmaf(a.z, bb.z, acc[2][2]); acc[2][3] = fmaf(a.z, bb.w, acc[2][3]);
            acc[3][0] = fmaf(a.w, bb.x, acc[3][0]); acc[3][1] = fmaf(a.w, bb.y, acc[3][1]);
            acc[3][2] = fmaf(a.w, bb.z, acc[3][2]); acc[3][3] = fmaf(a.w, bb.w, acc[3][3]);
        }
    }
    __syncthreads();
    #pragma unroll
    for (int i = 0; i < 4; i++)
        #pragma unroll
        for (int j = 0; j < 4; j++)
            Ot[(tcol << 2) + j][(trow << 2) + i] = acc[i][j];
    __syncthreads();
    int b  = m0 >> 11;
    int l0 = m0 & (LEN - 1);
    for (int v = tid; v < 4096; v += 256){
        int cl = v >> 6, rl = v & 63;
        out[(size_t)b * DMODEL * LEN + (size_t)(n0 + cl) * LEN + l0 + rl] = Ot[cl][rl];
    }
}

// ---------------------------------------------------------------------------
extern "C" void kernel_launch(void* const* d_in, const int* in_sizes, int n_in,
                              void* d_out, int out_size, void* d_ws, size_t ws_size,
                              hipStream_t stream) {
    const float* x          = (const float*)d_in[0];
    const float* proj_w     = (const float*)d_in[1];
    const float* in_proj_w  = (const float*)d_in[2];
    const float* conv_w     = (const float*)d_in[3];
    const float* conv_b     = (const float*)d_in[4];
    const float* dt_bias    = (const float*)d_in[5];
    const float* A_log      = (const float*)d_in[6];
    const float* D_skip     = (const float*)d_in[7];
    const float* norm_w     = (const float*)d_in[8];
    const float* out_proj_w = (const float*)d_in[9];
    float* out = (float*)d_out;

    // u (fp32, == out_size) lives in d_out; dead before k_outproj writes out.
    float* u = out;

    // Workspace layout (bytes), total 46,268,416 (~44.1 MiB, < 48.9 known-ok):
    char* wsb = (char*)d_ws;
    __half* z_h    = (__half*)(wsb);                   // 12,582,912
    __half* xbc_h  = (__half*)(wsb + 12582912);        // 13,107,200
    __half* y_h    = xbc_h;                            // alias: xbc dead after dwconv
    __half* xcc_h  = (__half*)(wsb + 25690112);        // 13,107,200
    __half* dt_h   = (__half*)(wsb + 38797312);        //  4,194,304
    __half* cstate = (__half*)(wsb + 42991616);        //  3,145,728 (B*NH*NCHUNK*48)
    float*  dsum   = (float*)(wsb + 46137344);         //    131,072 (B*NH*NCHUNK)

    k_convproj<<<256, 256, 0, stream>>>(x, proj_w, u);
    k_inproj  <<<dim3(128, 29), 256, 0, stream>>>(u, in_proj_w, dt_bias, z_h, xbc_h, dt_h);
    k_dwconv  <<<25600, 256, 0, stream>>>(xbc_h, conv_w, conv_b, xcc_h);
    k_scanA   <<<8192, 64, 0, stream>>>(dt_h, xcc_h, A_log, cstate, dsum);
    k_scanB   <<<1024, 64, 0, stream>>>(cstate, dsum);
    k_scanC   <<<8192, 64, 0, stream>>>(dt_h, xcc_h, A_log, D_skip, cstate, y_h);
    k_norm    <<<8192, 256, 0, stream>>>(y_h, z_h, norm_w);
    k_outproj <<<dim3(128, 4), 256, 0, stream>>>(y_h, out_proj_w, out);
}

// Round 5
// 318.532 us; speedup vs baseline: 3.8034x; 1.3604x over previous
//
#include <hip/hip_runtime.h>
#include <hip/hip_fp16.h>
#include <math.h>

// Problem constants
#define B_     4
#define CIN    128
#define LEN    2048
#define DMODEL 256
#define DSTATE 16
#define NHEADS 256
#define DINNER 768
#define CONVDIM 800      // DINNER + 2*DSTATE
#define DINPROJ 1824     // 2*DINNER + 2*DSTATE + NHEADS
#define EPS_   1e-5f
#define CHUNK  64
#define NCHUNK 32        // LEN / CHUNK

typedef _Float16 f16x8 __attribute__((ext_vector_type(8)));
typedef float    f32x4 __attribute__((ext_vector_type(4)));

__device__ __forceinline__ float silu_(float x){ return x / (1.0f + __expf(-x)); }
__device__ __forceinline__ float softplus_(float x){
    return x > 0.f ? x + log1pf(__expf(-x)) : log1pf(__expf(x));
}

// async global->LDS, 16B per lane; LDS dest = wave-uniform base + lane*16
__device__ __forceinline__ void gl2lds16(const _Float16* g, _Float16* l){
    __builtin_amdgcn_global_load_lds(
        (const __attribute__((address_space(1))) void*)g,
        (__attribute__((address_space(3))) void*)l, 16, 0, 0);
}

// ---------------------------------------------------------------------------
// fp32 -> fp16 convert (weights), grid-stride
// ---------------------------------------------------------------------------
__global__ __launch_bounds__(256) void k_f2h(const float* __restrict__ a,
                                             _Float16* __restrict__ o, int n){
    for (int i = blockIdx.x * 256 + threadIdx.x; i < n; i += gridDim.x * 256)
        o[i] = (_Float16)a[i];
}

// ---------------------------------------------------------------------------
// im2col for the conv projection: xcol[(b,l)][(ci,k)] = x[b,ci,l-1+k], fp16.
// 64 l-values per block; pad zeros outside [0,LEN).
// ---------------------------------------------------------------------------
__global__ __launch_bounds__(256) void k_im2col(const float* __restrict__ x,
                                                _Float16* __restrict__ xcol){
    __shared__ float xs[CIN][68];      // 67 used
    int blk = blockIdx.x;              // 0..127
    int b  = blk >> 5;
    int l0 = (blk & 31) << 6;          // *64
    const float* xb = x + (size_t)b * CIN * LEN;
    for (int idx = threadIdx.x; idx < CIN * 67; idx += 256){
        int ci = idx / 67, j = idx % 67;
        int gl = l0 - 1 + j;
        xs[ci][j] = (gl >= 0 && gl < LEN) ? xb[ci * LEN + gl] : 0.f;
    }
    __syncthreads();
    #pragma unroll
    for (int v = 0; v < 16; v++){
        int id = v * 256 + threadIdx.x;   // 0..4095
        int rl = id >> 6, c = id & 63;    // row-in-tile, 16B chunk
        f16x8 pk;
        #pragma unroll
        for (int e = 0; e < 8; e++){
            int ci = c * 2 + (e >> 2), k = e & 3;
            pk[e] = (_Float16)xs[ci][rl + k];
        }
        *(f16x8*)&xcol[((size_t)(b * LEN + l0 + rl)) * 512 + c * 8] = pk;
    }
}

// ---------------------------------------------------------------------------
// Shared MFMA GEMM: C[M][N] = A[M][K] . Bw[N][K]^T, f16 inputs, fp32 acc.
// 128x128 tile, BK=32, 4 waves (2x2), each wave 4x4 mfma_f32_16x16x32_f16.
// EPI 0: u_h fp16 [M][256]         (conv projection)
// EPI 1: split z/xbc/dt(+softplus) (in_proj; N=1824, B-rows clamped)
// EPI 2: fp32 transposed (B,D,L)   (out_proj)
// ---------------------------------------------------------------------------
template<int K, int EPI>
__global__ __launch_bounds__(256) void k_gemm(const _Float16* __restrict__ A,
                                              const _Float16* __restrict__ Bw,
                                              const float* __restrict__ dt_bias,
                                              _Float16* __restrict__ o_u,
                                              _Float16* __restrict__ o_z,
                                              _Float16* __restrict__ o_xbc,
                                              _Float16* __restrict__ o_dt,
                                              float* __restrict__ o_f){
    __shared__ __align__(16) _Float16 As[128 * 32];
    __shared__ __align__(16) _Float16 Bs[128 * 32];
    int tid  = threadIdx.x;
    int wv   = tid >> 6;
    int lane = tid & 63;
    int quad = lane >> 4;
    int l16  = lane & 15;
    int m0 = blockIdx.x * 128;
    int n0 = blockIdx.y * 128;
    int wm = (wv >> 1) * 64;
    int wn = (wv & 1) * 64;
    int srow = lane >> 2;              // 0..15 staging row
    int scol = (lane & 3) * 8;         // halves offset 0,8,16,24

    f32x4 acc[4][4];
    #pragma unroll
    for (int i = 0; i < 4; i++)
        #pragma unroll
        for (int j = 0; j < 4; j++)
            acc[i][j] = (f32x4){0.f, 0.f, 0.f, 0.f};

    for (int k0 = 0; k0 < K; k0 += 32){
        #pragma unroll
        for (int j = 0; j < 2; j++){
            int ar = m0 + wv * 32 + j * 16 + srow;
            gl2lds16(A + (size_t)ar * K + k0 + scol,
                     &As[(wv * 32 + j * 16) * 32]);
            int nr = n0 + wv * 32 + j * 16 + srow;
            if (EPI == 1) nr = nr > (DINPROJ - 1) ? (DINPROJ - 1) : nr;
            gl2lds16(Bw + (size_t)nr * K + k0 + scol,
                     &Bs[(wv * 32 + j * 16) * 32]);
        }
        __syncthreads();               // vmcnt(0) drain before barrier
        f16x8 af[4], bf[4];
        #pragma unroll
        for (int i = 0; i < 4; i++)
            af[i] = *(const f16x8*)&As[(wm + i * 16 + l16) * 32 + quad * 8];
        #pragma unroll
        for (int j = 0; j < 4; j++)
            bf[j] = *(const f16x8*)&Bs[(wn + j * 16 + l16) * 32 + quad * 8];
        #pragma unroll
        for (int i = 0; i < 4; i++)
            #pragma unroll
            for (int j = 0; j < 4; j++)
                acc[i][j] = __builtin_amdgcn_mfma_f32_16x16x32_f16(
                                af[i], bf[j], acc[i][j], 0, 0, 0);
        __syncthreads();
    }

    if (EPI == 0){
        #pragma unroll
        for (int j = 0; j < 4; j++){
            int col = n0 + wn + j * 16 + l16;
            #pragma unroll
            for (int i = 0; i < 4; i++){
                int row = m0 + wm + i * 16 + quad * 4;
                #pragma unroll
                for (int r = 0; r < 4; r++)
                    o_u[(size_t)(row + r) * DMODEL + col] = (_Float16)acc[i][j][r];
            }
        }
    } else if (EPI == 1){
        #pragma unroll
        for (int j = 0; j < 4; j++){
            int col = n0 + wn + j * 16 + l16;
            if (col < DINNER){
                #pragma unroll
                for (int i = 0; i < 4; i++){
                    int row = m0 + wm + i * 16 + quad * 4;
                    #pragma unroll
                    for (int r = 0; r < 4; r++)
                        o_z[(size_t)(row + r) * DINNER + col] = (_Float16)acc[i][j][r];
                }
            } else if (col < DINNER + CONVDIM){
                int cc = col - DINNER;
                #pragma unroll
                for (int i = 0; i < 4; i++){
                    int row = m0 + wm + i * 16 + quad * 4;
                    #pragma unroll
                    for (int r = 0; r < 4; r++)
                        o_xbc[(size_t)(row + r) * CONVDIM + cc] = (_Float16)acc[i][j][r];
                }
            } else if (col < DINPROJ){
                int hh = col - (DINNER + CONVDIM);
                float bias = dt_bias[hh];
                #pragma unroll
                for (int i = 0; i < 4; i++){
                    int row = m0 + wm + i * 16 + quad * 4;
                    #pragma unroll
                    for (int r = 0; r < 4; r++)
                        o_dt[(size_t)(row + r) * NHEADS + hh] =
                            (_Float16)softplus_(acc[i][j][r] + bias);
                }
            }
        }
    } else {
        #pragma unroll
        for (int i = 0; i < 4; i++){
            int row = m0 + wm + i * 16 + quad * 4;
            int b = row >> 11, l = row & (LEN - 1);
            #pragma unroll
            for (int j = 0; j < 4; j++){
                int d = n0 + wn + j * 16 + l16;
                *(f32x4*)&o_f[(((size_t)(b * DMODEL + d)) << 11) + l] = acc[i][j];
            }
        }
    }
}

// ---------------------------------------------------------------------------
// depthwise causal conv (4-tap) + bias + SiLU, fp16 in/out.
// ---------------------------------------------------------------------------
__global__ __launch_bounds__(256) void k_dwconv(const __half* __restrict__ xbc,
                                                const float* __restrict__ cw,
                                                const float* __restrict__ cb,
                                                __half* __restrict__ xcc){
    int idx = blockIdx.x * 256 + threadIdx.x;   // < 8192*800
    int c = idx % CONVDIM;
    int r = idx / CONVDIM;
    int l = r & (LEN - 1);
    float4 wv = *(const float4*)(cw + c * 4);
    float acc = cb[c];
    if (l >= 3){
        const __half* base = xbc + (size_t)(r - 3) * CONVDIM + c;
        acc += __half2float(base[0]) * wv.x + __half2float(base[CONVDIM]) * wv.y +
               __half2float(base[2 * CONVDIM]) * wv.z + __half2float(base[3 * CONVDIM]) * wv.w;
    } else {
        const float wk[4] = {wv.x, wv.y, wv.z, wv.w};
        for (int k = 0; k < 4; k++){
            int t = l - 3 + k;
            if (t >= 0) acc += __half2float(xbc[(size_t)(r + k - 3) * CONVDIM + c]) * wk[k];
        }
    }
    xcc[idx] = __float2half(silu_(acc));
}

// ---------------------------------------------------------------------------
// scan pass A: per (b, head-group, chunk): recurrence from zero state;
// emit final local state (fp16) and chunk decay exp(A*sum(dt)).
// ---------------------------------------------------------------------------
__global__ __launch_bounds__(64) void k_scanA(const __half* __restrict__ dtb,
                                              const __half* __restrict__ xcc,
                                              const float* __restrict__ A_log,
                                              __half* __restrict__ cstate,
                                              float* __restrict__ dsum){
    int blk = blockIdx.x;              // 0..8191
    int c  = blk & (NCHUNK - 1);
    int hg = (blk >> 5) & 63;
    int b  = blk >> 11;
    int lane = threadIdx.x;
    int hl = lane >> 4;
    int n  = lane & 15;
    int h  = hg * 4 + hl;
    int c0 = h * 3;
    float A = -__expf(A_log[h]);
    int t0 = c * CHUNK;
    const __half* xr  = xcc + ((size_t)b * LEN + t0) * CONVDIM;
    const __half* dtp = dtb + ((size_t)b * LEN + t0) * NHEADS + h;
    float h0 = 0.f, h1 = 0.f, h2 = 0.f, sdt = 0.f;
    for (int t = 0; t < CHUNK; t++){
        float vx0 = __half2float(xr[c0]);
        float vx1 = __half2float(xr[c0 + 1]);
        float vx2 = __half2float(xr[c0 + 2]);
        float vB  = __half2float(xr[DINNER + n]);
        float cdt = __half2float(dtp[(size_t)t * NHEADS]);
        float dA  = __expf(cdt * A);
        float dtB = cdt * vB;
        h0 = fmaf(h0, dA, vx0 * dtB);
        h1 = fmaf(h1, dA, vx1 * dtB);
        h2 = fmaf(h2, dA, vx2 * dtB);
        sdt += cdt;
        xr += CONVDIM;
    }
    size_t sbase = (((size_t)(b * NHEADS + h)) * NCHUNK + c) * 48;
    cstate[sbase + n]      = __float2half(h0);
    cstate[sbase + 16 + n] = __float2half(h1);
    cstate[sbase + 32 + n] = __float2half(h2);
    if (n == 0) dsum[(size_t)(b * NHEADS + h) * NCHUNK + c] = __expf(A * sdt);
}

// ---------------------------------------------------------------------------
// scan pass B: per (b,h), combine chunk summaries sequentially; overwrite
// cstate[c] in place with the INITIAL state of chunk c.
// ---------------------------------------------------------------------------
__global__ __launch_bounds__(64) void k_scanB(__half* __restrict__ cstate,
                                              const float* __restrict__ dsum){
    int bh = blockIdx.x;               // 0..1023
    int lane = threadIdx.x;
    if (lane >= 48) return;
    __half* st = cstate + (size_t)bh * NCHUNK * 48 + lane;
    const float* dd = dsum + (size_t)bh * NCHUNK;
    float H = 0.f;
    for (int c = 0; c < NCHUNK; c++){
        float d = dd[c];
        float s = __half2float(st[(size_t)c * 48]);
        st[(size_t)c * 48] = __float2half(H);
        H = fmaf(H, d, s);
    }
}

// ---------------------------------------------------------------------------
// scan pass C: recurrence from correct initial state; y = reduce_n(h*C) +
// D_skip*x, via shfl reduction over the 16 state lanes.
// ---------------------------------------------------------------------------
__global__ __launch_bounds__(64) void k_scanC(const __half* __restrict__ dtb,
                                              const __half* __restrict__ xcc,
                                              const float* __restrict__ A_log,
                                              const float* __restrict__ D_skip,
                                              const __half* __restrict__ cstate,
                                              __half* __restrict__ y){
    int blk = blockIdx.x;              // 0..8191
    int c  = blk & (NCHUNK - 1);
    int hg = (blk >> 5) & 63;
    int b  = blk >> 11;
    int lane = threadIdx.x;
    int hl = lane >> 4;
    int n  = lane & 15;
    int h  = hg * 4 + hl;
    int c0 = h * 3;
    float A   = -__expf(A_log[h]);
    float Dsk = D_skip[h];
    int t0 = c * CHUNK;
    const __half* xr  = xcc + ((size_t)b * LEN + t0) * CONVDIM;
    const __half* dtp = dtb + ((size_t)b * LEN + t0) * NHEADS + h;
    size_t sbase = (((size_t)(b * NHEADS + h)) * NCHUNK + c) * 48;
    float h0 = __half2float(cstate[sbase + n]);
    float h1 = __half2float(cstate[sbase + 16 + n]);
    float h2 = __half2float(cstate[sbase + 32 + n]);
    __half* yp = y + ((size_t)b * LEN + t0) * DINNER + c0;
    for (int t = 0; t < CHUNK; t++){
        float vx0 = __half2float(xr[c0]);
        float vx1 = __half2float(xr[c0 + 1]);
        float vx2 = __half2float(xr[c0 + 2]);
        float vB  = __half2float(xr[DINNER + n]);
        float vC  = __half2float(xr[DINNER + DSTATE + n]);
        float cdt = __half2float(dtp[(size_t)t * NHEADS]);
        float dA  = __expf(cdt * A);
        float dtB = cdt * vB;
        h0 = fmaf(h0, dA, vx0 * dtB);
        h1 = fmaf(h1, dA, vx1 * dtB);
        h2 = fmaf(h2, dA, vx2 * dtB);
        float p0 = h0 * vC, p1 = h1 * vC, p2 = h2 * vC;
        #pragma unroll
        for (int m = 1; m < 16; m <<= 1){
            p0 += __shfl_xor(p0, m, 64);
            p1 += __shfl_xor(p1, m, 64);
            p2 += __shfl_xor(p2, m, 64);
        }
        if (n < 3){
            float pv = (n == 0) ? p0 : ((n == 1) ? p1 : p2);
            float xv = (n == 0) ? vx0 : ((n == 1) ? vx1 : vx2);
            yp[n] = __float2half(fmaf(Dsk, xv, pv));
        }
        xr += CONVDIM;
        yp += DINNER;
    }
}

// ---------------------------------------------------------------------------
// gated RMSNorm (in place on y, fp16 storage, fp32 math)
// ---------------------------------------------------------------------------
__global__ __launch_bounds__(256) void k_norm(__half* __restrict__ y,
                                              const __half* __restrict__ z,
                                              const float* __restrict__ nw){
    __shared__ float wsum[4];
    size_t r = blockIdx.x;
    int tid = threadIdx.x;
    const __half* zr = z + r * DINNER;
    __half* yr = y + r * DINNER;
    int e0 = tid, e1 = tid + 256, e2 = tid + 512;
    float t0 = __half2float(yr[e0]) * silu_(__half2float(zr[e0]));
    float t1 = __half2float(yr[e1]) * silu_(__half2float(zr[e1]));
    float t2 = __half2float(yr[e2]) * silu_(__half2float(zr[e2]));
    float ss = t0 * t0 + t1 * t1 + t2 * t2;
    #pragma unroll
    for (int m = 1; m < 64; m <<= 1) ss += __shfl_xor(ss, m, 64);
    if ((tid & 63) == 0) wsum[tid >> 6] = ss;
    __syncthreads();
    float tot = wsum[0] + wsum[1] + wsum[2] + wsum[3];
    float sc = rsqrtf(tot / (float)DINNER + EPS_);
    yr[e0] = __float2half(t0 * sc * nw[e0]);
    yr[e1] = __float2half(t1 * sc * nw[e1]);
    yr[e2] = __float2half(t2 * sc * nw[e2]);
}

// ---------------------------------------------------------------------------
extern "C" void kernel_launch(void* const* d_in, const int* in_sizes, int n_in,
                              void* d_out, int out_size, void* d_ws, size_t ws_size,
                              hipStream_t stream) {
    const float* x          = (const float*)d_in[0];
    const float* proj_w     = (const float*)d_in[1];
    const float* in_proj_w  = (const float*)d_in[2];
    const float* conv_w     = (const float*)d_in[3];
    const float* conv_b     = (const float*)d_in[4];
    const float* dt_bias    = (const float*)d_in[5];
    const float* A_log      = (const float*)d_in[6];
    const float* D_skip     = (const float*)d_in[7];
    const float* norm_w     = (const float*)d_in[8];
    const float* out_proj_w = (const float*)d_in[9];
    float* out = (float*)d_out;

    // fp16 proj/in_proj weights live in d_out (dead until k_gemm<768,2>
    // overwrites all of d_out with the final result).
    char* ob = (char*)d_out;
    _Float16* pw_h  = (_Float16*)ob;                   //   262,144 B (256x512)
    _Float16* ipw_h = (_Float16*)(ob + 262144);        //   933,888 B (1824x256)

    // Workspace (bytes), total 46,661,632 (~44.5 MiB, <= 48.9 MiB known-good):
    //   region1 [0, 13,107,200): xcol (8,388,608) + u_h (4,194,304), both dead
    //   after in_proj; xcc aliases the whole region afterwards.
    char* wsb = (char*)d_ws;
    _Float16* xcol  = (_Float16*)(wsb);                // 8192x512 fp16
    _Float16* u_h   = (_Float16*)(wsb + 8388608);      // 8192x256 fp16
    __half*   xcc_h = (__half*)(wsb);                  // 8192x800 fp16 (alias)
    __half*   z_h   = (__half*)(wsb + 13107200);       // 8192x768
    __half*   xbc_h = (__half*)(wsb + 25690112);       // 8192x800
    __half*   y_h   = xbc_h;                           // alias: xbc dead after dwconv
    __half*   dt_h  = (__half*)(wsb + 38797312);       // 8192x256
    __half*   cstate= (__half*)(wsb + 42991616);       // B*NH*NCHUNK*48
    float*    dsum  = (float*)(wsb + 46137344);        // B*NH*NCHUNK
    _Float16* opw_h = (_Float16*)(wsb + 46268416);     // 256x768 fp16

    k_f2h   <<<64, 256, 0, stream>>>(proj_w,     pw_h,  DMODEL * CIN * 4);
    k_f2h   <<<64, 256, 0, stream>>>(in_proj_w,  ipw_h, DINPROJ * DMODEL);
    k_f2h   <<<64, 256, 0, stream>>>(out_proj_w, opw_h, DMODEL * DINNER);
    k_im2col<<<128, 256, 0, stream>>>(x, xcol);
    k_gemm<512, 0><<<dim3(64, 2), 256, 0, stream>>>(xcol, pw_h, nullptr,
        u_h, nullptr, nullptr, nullptr, nullptr);
    k_gemm<256, 1><<<dim3(64, 15), 256, 0, stream>>>(u_h, ipw_h, dt_bias,
        nullptr, (_Float16*)z_h, (_Float16*)xbc_h, (_Float16*)dt_h, nullptr);
    k_dwconv<<<25600, 256, 0, stream>>>(xbc_h, conv_w, conv_b, xcc_h);
    k_scanA <<<8192, 64, 0, stream>>>(dt_h, xcc_h, A_log, cstate, dsum);
    k_scanB <<<1024, 64, 0, stream>>>(cstate, dsum);
    k_scanC <<<8192, 64, 0, stream>>>(dt_h, xcc_h, A_log, D_skip, cstate, y_h);
    k_norm  <<<8192, 256, 0, stream>>>(y_h, z_h, norm_w);
    k_gemm<768, 2><<<dim3(64, 2), 256, 0, stream>>>((const _Float16*)y_h, opw_h,
        nullptr, nullptr, nullptr, nullptr, nullptr, out);
}